// Round 4
// baseline (269.082 us; speedup 1.0000x reference)
//
#include <hip/hip_runtime.h>
#include <hip/hip_bf16.h>
#include <stdint.h>

#define NN 50000
#define NE 1600000
#define BSH 7            // bucket = 128 dst nodes
#define NBK 391          // ceil(NN/128)
#define NSB 512          // scatter blocks
#define ECH 3125         // edges per scatter block (NSB*ECH == NE exactly)

// ---------------- bucketed edge sort ----------------
// pass A: per-block bucket histogram
__global__ __launch_bounds__(256) void k_hist(const int* __restrict__ dst, int* __restrict__ bh){
  __shared__ int h[NBK];
  for (int i = threadIdx.x; i < NBK; i += 256) h[i] = 0;
  __syncthreads();
  int e0 = blockIdx.x * ECH;
  for (int e = e0 + threadIdx.x; e < e0 + ECH; e += 256)
    atomicAdd(&h[dst[e] >> BSH], 1);
  __syncthreads();
  for (int i = threadIdx.x; i < NBK; i += 256)
    bh[i * NSB + blockIdx.x] = h[i];
}

// per-bucket exclusive scan across the NSB blocks
__global__ __launch_bounds__(512) void k_bscan(const int* __restrict__ bh, int* __restrict__ boff,
                                               int* __restrict__ btot){
  __shared__ int lds[NSB];
  int b = blockIdx.x;
  int v = bh[b * NSB + threadIdx.x];
  lds[threadIdx.x] = v;
  __syncthreads();
  for (int ofs = 1; ofs < NSB; ofs <<= 1){
    int t = (threadIdx.x >= ofs) ? lds[threadIdx.x - ofs] : 0;
    __syncthreads();
    lds[threadIdx.x] += t;
    __syncthreads();
  }
  boff[b * NSB + threadIdx.x] = lds[threadIdx.x] - v;
  if (threadIdx.x == NSB - 1) btot[b] = lds[NSB - 1];
}

// exclusive scan of bucket totals
__global__ __launch_bounds__(512) void k_btscan(const int* __restrict__ btot, int* __restrict__ bbase){
  __shared__ int lds[512];
  int v = (threadIdx.x < NBK) ? btot[threadIdx.x] : 0;
  lds[threadIdx.x] = v;
  __syncthreads();
  for (int ofs = 1; ofs < 512; ofs <<= 1){
    int t = (threadIdx.x >= ofs) ? lds[threadIdx.x - ofs] : 0;
    __syncthreads();
    lds[threadIdx.x] += t;
    __syncthreads();
  }
  if (threadIdx.x < NBK) bbase[threadIdx.x] = lds[threadIdx.x] - v;
  if (threadIdx.x == NBK - 1) bbase[NBK] = lds[threadIdx.x];
}

// pass B: scatter packed (src<<16 | dst) into bucket-sorted ebuf
__global__ __launch_bounds__(256) void k_scatter(const int* __restrict__ src, const int* __restrict__ dst,
                                                 const int* __restrict__ bbase, const int* __restrict__ boff,
                                                 uint32_t* __restrict__ ebuf){
  __shared__ int ctr[NBK];
  for (int i = threadIdx.x; i < NBK; i += 256)
    ctr[i] = bbase[i] + boff[i * NSB + blockIdx.x];
  __syncthreads();
  int e0 = blockIdx.x * ECH;
  for (int e = e0 + threadIdx.x; e < e0 + ECH; e += 256){
    int d = dst[e];
    int s = src[e];
    int p = atomicAdd(&ctr[d >> BSH], 1);
    ebuf[p] = ((uint32_t)s << 16) | (uint32_t)d;
  }
}

// per-bucket in-degree -> dinv = rsqrt(deg+1)
__global__ __launch_bounds__(256) void k_bdeg(const uint32_t* __restrict__ ebuf, const int* __restrict__ bbase,
                                              float* __restrict__ dinv){
  __shared__ int h[128];
  if (threadIdx.x < 128) h[threadIdx.x] = 0;
  __syncthreads();
  int b = blockIdx.x;
  int e0 = bbase[b], e1 = bbase[b + 1];
  for (int e = e0 + threadIdx.x; e < e1; e += 256)
    atomicAdd(&h[ebuf[e] & 127], 1);
  __syncthreads();
  int node = (b << BSH) + threadIdx.x;
  if (threadIdx.x < 128 && node < NN)
    dinv[node] = rsqrtf((float)(h[threadIdx.x] + 1));
}

// ---------------- collapsed weights ----------------
// M1 = W2@Wc [128,8]; Wcombo = W1@M1 [256,8]; c1 = M1^T b1; c2 = Wc^T b2 + bc
__global__ __launch_bounds__(256) void k_wcombo(const float* __restrict__ W1, const float* __restrict__ b1,
                                                const float* __restrict__ W2, const float* __restrict__ b2,
                                                const float* __restrict__ Wc, const float* __restrict__ bc,
                                                float* __restrict__ Wcombo, float* __restrict__ c12){
  __shared__ float M1[128 * 8];
  int t = threadIdx.x;
  for (int idx = t; idx < 1024; idx += 256){
    int k = idx >> 3, c = idx & 7;
    float s = 0.f;
    for (int j = 0; j < 64; ++j) s += W2[k * 64 + j] * Wc[j * 8 + c];
    M1[idx] = s;
  }
  __syncthreads();
  for (int idx = t; idx < 2048; idx += 256){
    int i = idx >> 3, c = idx & 7;
    float s = 0.f;
    for (int k = 0; k < 128; ++k) s += W1[i * 128 + k] * M1[k * 8 + c];
    Wcombo[idx] = s;
  }
  if (t < 8){
    float s = 0.f;
    for (int k = 0; k < 128; ++k) s += b1[k] * M1[k * 8 + t];
    c12[t] = s;
  } else if (t < 16){
    int c = t - 8;
    float s = bc[c];
    for (int k = 0; k < 64; ++k) s += b2[k] * Wc[k * 8 + c];
    c12[t] = s;
  }
}

// ---------------- Y' = dinv ⊙ (X @ Wcombo)  [NN, 8] ----------------
__global__ __launch_bounds__(256) void k_y(const float* __restrict__ X, const float* __restrict__ Wcombo,
                                           const float* __restrict__ dinv, float* __restrict__ Yp){
  __shared__ float Wl[2048];
  int t = threadIdx.x;
  for (int i = t; i < 2048; i += 256) Wl[i] = Wcombo[i];
  __syncthreads();
  int gid = blockIdx.x * 256 + t;
  int row = gid >> 3, c = gid & 7;
  if (row >= NN) return;
  const float* Xr = X + (size_t)row * 256;
  float acc = 0.f;
  #pragma unroll 8
  for (int k = 0; k < 256; k += 4){
    float4 x = *(const float4*)(Xr + k);
    acc += x.x * Wl[k * 8 + c] + x.y * Wl[(k + 1) * 8 + c]
         + x.z * Wl[(k + 2) * 8 + c] + x.w * Wl[(k + 3) * 8 + c];
  }
  Yp[(size_t)row * 8 + c] = acc * dinv[row];
}

// ---------------- aggregation pass 1: U = dinv^2 ⊙ ((A+I)Y'), V = dinv ⊙ ((A+I)dinv) ----------------
__global__ __launch_bounds__(256) void k_aggp1(const uint32_t* __restrict__ ebuf, const int* __restrict__ bbase,
                                               const float* __restrict__ dinv, const float* __restrict__ Yp,
                                               float* __restrict__ U, float* __restrict__ V){
  __shared__ float acc[128 * 9];
  int t = threadIdx.x;
  for (int i = t; i < 1152; i += 256) acc[i] = 0.f;
  __syncthreads();
  int b = blockIdx.x;
  int e0 = bbase[b], e1 = bbase[b + 1];
  for (int e = e0 + t; e < e1; e += 256){
    uint32_t pv = ebuf[e];
    int s = pv >> 16;
    int dl = pv & 127;
    float4 y0 = *(const float4*)(Yp + (size_t)s * 8);
    float4 y1 = *(const float4*)(Yp + (size_t)s * 8 + 4);
    float ds = dinv[s];
    float* a = &acc[dl * 9];
    atomicAdd(a + 0, y0.x); atomicAdd(a + 1, y0.y);
    atomicAdd(a + 2, y0.z); atomicAdd(a + 3, y0.w);
    atomicAdd(a + 4, y1.x); atomicAdd(a + 5, y1.y);
    atomicAdd(a + 6, y1.z); atomicAdd(a + 7, y1.w);
    atomicAdd(a + 8, ds);
  }
  __syncthreads();
  int node0 = b << BSH;
  for (int i = t; i < 1024; i += 256){
    int ln = i >> 3, c = i & 7;
    int node = node0 + ln;
    if (node < NN){
      float di = dinv[node];
      U[(size_t)node * 8 + c] = di * di * (acc[ln * 9 + c] + Yp[(size_t)node * 8 + c]);
    }
  }
  if (t < 128){
    int node = node0 + t;
    if (node < NN){
      float di = dinv[node];
      V[node] = di * (acc[t * 9 + 8] + di);
    }
  }
}

// ---------------- aggregation pass 2: out = dinv ⊙ ((A+I)U) + V·c1 + c2 ----------------
__global__ __launch_bounds__(256) void k_aggp2(const uint32_t* __restrict__ ebuf, const int* __restrict__ bbase,
                                               const float* __restrict__ dinv, const float* __restrict__ U,
                                               const float* __restrict__ V, const float* __restrict__ c12,
                                               float* __restrict__ O){
  __shared__ float acc[128 * 9];   // stride 9 for bank spread; col 8 unused
  __shared__ float c1s[8], c2s[8];
  int t = threadIdx.x;
  if (t < 8) c1s[t] = c12[t];
  else if (t < 16) c2s[t - 8] = c12[t];
  for (int i = t; i < 1152; i += 256) acc[i] = 0.f;
  __syncthreads();
  int b = blockIdx.x;
  int e0 = bbase[b], e1 = bbase[b + 1];
  for (int e = e0 + t; e < e1; e += 256){
    uint32_t pv = ebuf[e];
    int s = pv >> 16;
    int dl = pv & 127;
    float4 y0 = *(const float4*)(U + (size_t)s * 8);
    float4 y1 = *(const float4*)(U + (size_t)s * 8 + 4);
    float* a = &acc[dl * 9];
    atomicAdd(a + 0, y0.x); atomicAdd(a + 1, y0.y);
    atomicAdd(a + 2, y0.z); atomicAdd(a + 3, y0.w);
    atomicAdd(a + 4, y1.x); atomicAdd(a + 5, y1.y);
    atomicAdd(a + 6, y1.z); atomicAdd(a + 7, y1.w);
  }
  __syncthreads();
  int node0 = b << BSH;
  for (int i = t; i < 1024; i += 256){
    int ln = i >> 3, c = i & 7;
    int node = node0 + ln;
    if (node < NN){
      float di = dinv[node];
      O[(size_t)node * 8 + c] = di * (acc[ln * 9 + c] + U[(size_t)node * 8 + c])
                              + V[node] * c1s[c] + c2s[c];
    }
  }
}

extern "C" void kernel_launch(void* const* d_in, const int* in_sizes, int n_in,
                              void* d_out, int out_size, void* d_ws, size_t ws_size,
                              hipStream_t stream) {
  const float* seq = (const float*)d_in[0];
  const int*   ei  = (const int*)d_in[1];
  const int*   esrc = ei;
  const int*   edst = ei + NE;
  const float* W1 = (const float*)d_in[2];
  const float* b1 = (const float*)d_in[3];
  const float* W2 = (const float*)d_in[4];
  const float* b2 = (const float*)d_in[5];
  const float* Wc = (const float*)d_in[6];
  const float* bc = (const float*)d_in[7];
  float* out = (float*)d_out;

  char* ws = (char*)d_ws;
  size_t o = 0;
  auto alloc = [&](size_t bytes) -> void* {
    void* p = ws + o;
    o += (bytes + 255) & ~(size_t)255;
    return p;
  };
  int*      bh    = (int*)alloc((size_t)NBK * NSB * 4);
  int*      boff  = (int*)alloc((size_t)NBK * NSB * 4);
  int*      btot  = (int*)alloc((size_t)NBK * 4);
  int*      bbase = (int*)alloc((size_t)(NBK + 1) * 4);
  uint32_t* ebuf  = (uint32_t*)alloc((size_t)NE * 4);
  float*    dinv  = (float*)alloc((size_t)NN * 4);
  float*    Wcb   = (float*)alloc(2048 * 4);
  float*    c12   = (float*)alloc(16 * 4);
  float*    Yp    = (float*)alloc((size_t)NN * 8 * 4);
  float*    U     = (float*)alloc((size_t)NN * 8 * 4);
  float*    V     = (float*)alloc((size_t)NN * 4);

  k_hist   <<<NSB, 256, 0, stream>>>(edst, bh);
  k_bscan  <<<NBK, NSB, 0, stream>>>(bh, boff, btot);
  k_btscan <<<1, 512, 0, stream>>>(btot, bbase);
  k_scatter<<<NSB, 256, 0, stream>>>(esrc, edst, bbase, boff, ebuf);
  k_bdeg   <<<NBK, 256, 0, stream>>>(ebuf, bbase, dinv);
  k_wcombo <<<1, 256, 0, stream>>>(W1, b1, W2, b2, Wc, bc, Wcb, c12);
  k_y      <<<(NN * 8 + 255) / 256, 256, 0, stream>>>(seq, Wcb, dinv, Yp);
  k_aggp1  <<<NBK, 256, 0, stream>>>(ebuf, bbase, dinv, Yp, U, V);
  k_aggp2  <<<NBK, 256, 0, stream>>>(ebuf, bbase, dinv, U, V, c12, out);
}

// Round 5
// 143.828 us; speedup vs baseline: 1.8709x; 1.8709x over previous
//
#include <hip/hip_runtime.h>
#include <hip/hip_bf16.h>
#include <stdint.h>

#define NN 50000
#define NE 1600000
#define BSH 8            // bucket = 256 dst nodes
#define NBK 196          // ceil(NN/256)
#define NSB 512          // scatter blocks
#define ECH 3125         // edges per scatter block (NSB*ECH == NE exactly)

// ---------------- bucketed edge sort ----------------
__global__ __launch_bounds__(256) void k_hist(const int* __restrict__ dst, int* __restrict__ bh){
  __shared__ int h[NBK];
  for (int i = threadIdx.x; i < NBK; i += 256) h[i] = 0;
  __syncthreads();
  int e0 = blockIdx.x * ECH;
  for (int e = e0 + threadIdx.x; e < e0 + ECH; e += 256)
    atomicAdd(&h[dst[e] >> BSH], 1);
  __syncthreads();
  for (int i = threadIdx.x; i < NBK; i += 256)
    bh[i * NSB + blockIdx.x] = h[i];
}

__global__ __launch_bounds__(512) void k_bscan(const int* __restrict__ bh, int* __restrict__ boff,
                                               int* __restrict__ btot){
  __shared__ int lds[NSB];
  int b = blockIdx.x;
  int v = bh[b * NSB + threadIdx.x];
  lds[threadIdx.x] = v;
  __syncthreads();
  for (int ofs = 1; ofs < NSB; ofs <<= 1){
    int t = (threadIdx.x >= ofs) ? lds[threadIdx.x - ofs] : 0;
    __syncthreads();
    lds[threadIdx.x] += t;
    __syncthreads();
  }
  boff[b * NSB + threadIdx.x] = lds[threadIdx.x] - v;
  if (threadIdx.x == NSB - 1) btot[b] = lds[NSB - 1];
}

__global__ __launch_bounds__(256) void k_btscan(const int* __restrict__ btot, int* __restrict__ bbase){
  __shared__ int lds[256];
  int v = (threadIdx.x < NBK) ? btot[threadIdx.x] : 0;
  lds[threadIdx.x] = v;
  __syncthreads();
  for (int ofs = 1; ofs < 256; ofs <<= 1){
    int t = (threadIdx.x >= ofs) ? lds[threadIdx.x - ofs] : 0;
    __syncthreads();
    lds[threadIdx.x] += t;
    __syncthreads();
  }
  if (threadIdx.x < NBK) bbase[threadIdx.x] = lds[threadIdx.x] - v;
  if (threadIdx.x == NBK - 1) bbase[NBK] = lds[threadIdx.x];
}

__global__ __launch_bounds__(256) void k_scatter(const int* __restrict__ src, const int* __restrict__ dst,
                                                 const int* __restrict__ bbase, const int* __restrict__ boff,
                                                 uint32_t* __restrict__ ebuf){
  __shared__ int ctr[NBK];
  for (int i = threadIdx.x; i < NBK; i += 256)
    ctr[i] = bbase[i] + boff[i * NSB + blockIdx.x];
  __syncthreads();
  int e0 = blockIdx.x * ECH;
  for (int e = e0 + threadIdx.x; e < e0 + ECH; e += 256){
    int d = dst[e];
    int s = src[e];
    int p = atomicAdd(&ctr[d >> BSH], 1);
    ebuf[p] = ((uint32_t)s << 16) | (uint32_t)d;
  }
}

// per-bucket in-degree -> deg, dinv = rsqrt(deg+1)
__global__ __launch_bounds__(256) void k_bdeg(const uint32_t* __restrict__ ebuf, const int* __restrict__ bbase,
                                              int* __restrict__ deg, float* __restrict__ dinv){
  __shared__ int h[256];
  h[threadIdx.x] = 0;
  __syncthreads();
  int b = blockIdx.x;
  int e0 = bbase[b], e1 = bbase[b + 1];
  for (int e = e0 + threadIdx.x; e < e1; e += 256)
    atomicAdd(&h[ebuf[e] & 255], 1);
  __syncthreads();
  int node = (b << BSH) + threadIdx.x;
  if (node < NN){
    int d = h[threadIdx.x];
    deg[node] = d;
    dinv[node] = rsqrtf((float)(d + 1));
  }
}

// node-degree scans -> offs
__global__ void k_scan1(const int* __restrict__ deg, int* __restrict__ offs, int* __restrict__ bsum){
  __shared__ int lds[1024];
  int i = blockIdx.x * 1024 + threadIdx.x;
  int v = (i < NN) ? deg[i] : 0;
  lds[threadIdx.x] = v;
  __syncthreads();
  for (int ofs = 1; ofs < 1024; ofs <<= 1){
    int t = (threadIdx.x >= ofs) ? lds[threadIdx.x - ofs] : 0;
    __syncthreads();
    lds[threadIdx.x] += t;
    __syncthreads();
  }
  if (i < NN) offs[i] = lds[threadIdx.x] - v;
  if (threadIdx.x == 1023) bsum[blockIdx.x] = lds[1023];
}

__global__ void k_scan2(int* __restrict__ bsum, int* __restrict__ offs, int nb){
  if (blockIdx.x == 0 && threadIdx.x == 0){
    int run = 0;
    for (int b = 0; b < nb; ++b){ int t = bsum[b]; bsum[b] = run; run += t; }
    offs[NN] = run;
  }
}

__global__ void k_scan3(int* __restrict__ offs, const int* __restrict__ bsum){
  int i = blockIdx.x * 1024 + threadIdx.x;
  if (i < NN) offs[i] += bsum[blockIdx.x];
}

// per-bucket CSR fill (ushort src), LDS counters
__global__ __launch_bounds__(256) void k_fill2(const uint32_t* __restrict__ ebuf, const int* __restrict__ bbase,
                                               const int* __restrict__ offs, unsigned short* __restrict__ csr){
  __shared__ int ctr[256];
  int b = blockIdx.x;
  int node = (b << BSH) + threadIdx.x;
  ctr[threadIdx.x] = (node < NN) ? offs[node] : 0;
  __syncthreads();
  int e0 = bbase[b], e1 = bbase[b + 1];
  for (int e = e0 + threadIdx.x; e < e1; e += 256){
    uint32_t v = ebuf[e];
    int p = atomicAdd(&ctr[v & 255], 1);
    csr[p] = (unsigned short)(v >> 16);
  }
}

// ---------------- collapsed weights ----------------
__global__ __launch_bounds__(256) void k_wcombo(const float* __restrict__ W1, const float* __restrict__ b1,
                                                const float* __restrict__ W2, const float* __restrict__ b2,
                                                const float* __restrict__ Wc, const float* __restrict__ bc,
                                                float* __restrict__ Wcombo, float* __restrict__ c12){
  __shared__ float M1[128 * 8];
  int t = threadIdx.x;
  for (int idx = t; idx < 1024; idx += 256){
    int k = idx >> 3, c = idx & 7;
    float s = 0.f;
    for (int j = 0; j < 64; ++j) s += W2[k * 64 + j] * Wc[j * 8 + c];
    M1[idx] = s;
  }
  __syncthreads();
  for (int idx = t; idx < 2048; idx += 256){
    int i = idx >> 3, c = idx & 7;
    float s = 0.f;
    for (int k = 0; k < 128; ++k) s += W1[i * 128 + k] * M1[k * 8 + c];
    Wcombo[idx] = s;
  }
  if (t < 8){
    float s = 0.f;
    for (int k = 0; k < 128; ++k) s += b1[k] * M1[k * 8 + t];
    c12[t] = s;
  } else if (t < 16){
    int c = t - 8;
    float s = bc[c];
    for (int k = 0; k < 64; ++k) s += b2[k] * Wc[k * 8 + c];
    c12[t] = s;
  }
}

// ---------------- Y' = dinv ⊙ (X @ Wcombo)  [NN, 8] ----------------
__global__ __launch_bounds__(256) void k_y(const float* __restrict__ X, const float* __restrict__ Wcombo,
                                           const float* __restrict__ dinv, float* __restrict__ Yp){
  __shared__ float Wl[2048];
  int t = threadIdx.x;
  for (int i = t; i < 2048; i += 256) Wl[i] = Wcombo[i];
  __syncthreads();
  int gid = blockIdx.x * 256 + t;
  int row = gid >> 3, c = gid & 7;
  if (row >= NN) return;
  const float* Xr = X + (size_t)row * 256;
  float acc = 0.f;
  #pragma unroll 8
  for (int k = 0; k < 256; k += 4){
    float4 x = *(const float4*)(Xr + k);
    acc += x.x * Wl[k * 8 + c] + x.y * Wl[(k + 1) * 8 + c]
         + x.z * Wl[(k + 2) * 8 + c] + x.w * Wl[(k + 3) * 8 + c];
  }
  Yp[(size_t)row * 8 + c] = acc * dinv[row];
}

// ---------------- agg pass 1 (segmented, no atomics) ----------------
// thread = (node, half); U = dinv^2*(sum_src Yp + Yp[self]); V = dinv*(sum_src dinv + dinv)
__global__ __launch_bounds__(256) void k_agg1(const unsigned short* __restrict__ csr, const int* __restrict__ offs,
                                              const float* __restrict__ dinv, const float* __restrict__ Yp,
                                              float* __restrict__ U, float* __restrict__ V){
  int gid = blockIdx.x * 256 + threadIdx.x;
  int node = gid >> 1, half = gid & 1;
  if (node >= NN) return;
  int e0 = offs[node], e1 = offs[node + 1];
  float4 a = {0.f, 0.f, 0.f, 0.f};
  float vd = 0.f;
  int e = e0;
  for (; e + 2 <= e1; e += 2){
    int s0 = csr[e], s1 = csr[e + 1];
    float4 y0 = *(const float4*)(Yp + (size_t)s0 * 8 + half * 4);
    float4 y1 = *(const float4*)(Yp + (size_t)s1 * 8 + half * 4);
    a.x += y0.x + y1.x; a.y += y0.y + y1.y;
    a.z += y0.z + y1.z; a.w += y0.w + y1.w;
    if (half == 0) vd += dinv[s0] + dinv[s1];
  }
  if (e < e1){
    int s0 = csr[e];
    float4 y0 = *(const float4*)(Yp + (size_t)s0 * 8 + half * 4);
    a.x += y0.x; a.y += y0.y; a.z += y0.z; a.w += y0.w;
    if (half == 0) vd += dinv[s0];
  }
  float di = dinv[node];
  float4 self = *(const float4*)(Yp + (size_t)node * 8 + half * 4);
  float s2 = di * di;
  float4 o;
  o.x = s2 * (a.x + self.x); o.y = s2 * (a.y + self.y);
  o.z = s2 * (a.z + self.z); o.w = s2 * (a.w + self.w);
  *(float4*)(U + (size_t)node * 8 + half * 4) = o;
  if (half == 0) V[node] = di * (vd + di);
}

// ---------------- agg pass 2: out = dinv*(sum_src U + U[self]) + V*c1 + c2 ----------------
__global__ __launch_bounds__(256) void k_agg2(const unsigned short* __restrict__ csr, const int* __restrict__ offs,
                                              const float* __restrict__ dinv, const float* __restrict__ U,
                                              const float* __restrict__ V, const float* __restrict__ c12,
                                              float* __restrict__ O){
  int gid = blockIdx.x * 256 + threadIdx.x;
  int node = gid >> 1, half = gid & 1;
  if (node >= NN) return;
  int e0 = offs[node], e1 = offs[node + 1];
  float4 a = {0.f, 0.f, 0.f, 0.f};
  int e = e0;
  for (; e + 2 <= e1; e += 2){
    int s0 = csr[e], s1 = csr[e + 1];
    float4 y0 = *(const float4*)(U + (size_t)s0 * 8 + half * 4);
    float4 y1 = *(const float4*)(U + (size_t)s1 * 8 + half * 4);
    a.x += y0.x + y1.x; a.y += y0.y + y1.y;
    a.z += y0.z + y1.z; a.w += y0.w + y1.w;
  }
  if (e < e1){
    int s0 = csr[e];
    float4 y0 = *(const float4*)(U + (size_t)s0 * 8 + half * 4);
    a.x += y0.x; a.y += y0.y; a.z += y0.z; a.w += y0.w;
  }
  float di = dinv[node];
  float4 self = *(const float4*)(U + (size_t)node * 8 + half * 4);
  float4 c1 = *(const float4*)(c12 + half * 4);
  float4 c2 = *(const float4*)(c12 + 8 + half * 4);
  float vn = V[node];
  float4 o;
  o.x = di * (a.x + self.x) + vn * c1.x + c2.x;
  o.y = di * (a.y + self.y) + vn * c1.y + c2.y;
  o.z = di * (a.z + self.z) + vn * c1.z + c2.z;
  o.w = di * (a.w + self.w) + vn * c1.w + c2.w;
  *(float4*)(O + (size_t)node * 8 + half * 4) = o;
}

extern "C" void kernel_launch(void* const* d_in, const int* in_sizes, int n_in,
                              void* d_out, int out_size, void* d_ws, size_t ws_size,
                              hipStream_t stream) {
  const float* seq = (const float*)d_in[0];
  const int*   ei  = (const int*)d_in[1];
  const int*   esrc = ei;
  const int*   edst = ei + NE;
  const float* W1 = (const float*)d_in[2];
  const float* b1 = (const float*)d_in[3];
  const float* W2 = (const float*)d_in[4];
  const float* b2 = (const float*)d_in[5];
  const float* Wc = (const float*)d_in[6];
  const float* bc = (const float*)d_in[7];
  float* out = (float*)d_out;

  char* ws = (char*)d_ws;
  size_t o = 0;
  auto alloc = [&](size_t bytes) -> void* {
    void* p = ws + o;
    o += (bytes + 255) & ~(size_t)255;
    return p;
  };
  int*      bh    = (int*)alloc((size_t)NBK * NSB * 4);
  int*      boff  = (int*)alloc((size_t)NBK * NSB * 4);
  int*      btot  = (int*)alloc((size_t)NBK * 4);
  int*      bbase = (int*)alloc((size_t)(NBK + 1) * 4);
  uint32_t* ebuf  = (uint32_t*)alloc((size_t)NE * 4);
  unsigned short* csr = (unsigned short*)alloc((size_t)NE * 2);
  int*      deg   = (int*)alloc((size_t)NN * 4);
  int*      offs  = (int*)alloc((size_t)(NN + 1) * 4);
  int*      bsum  = (int*)alloc(64 * 4);
  float*    dinv  = (float*)alloc((size_t)NN * 4);
  float*    Wcb   = (float*)alloc(2048 * 4);
  float*    c12   = (float*)alloc(16 * 4);
  float*    Yp    = (float*)alloc((size_t)NN * 8 * 4);
  float*    U     = (float*)alloc((size_t)NN * 8 * 4);
  float*    V     = (float*)alloc((size_t)NN * 4);

  const int nb = (NN + 1023) / 1024;
  k_hist   <<<NSB, 256, 0, stream>>>(edst, bh);
  k_bscan  <<<NBK, NSB, 0, stream>>>(bh, boff, btot);
  k_btscan <<<1, 256, 0, stream>>>(btot, bbase);
  k_scatter<<<NSB, 256, 0, stream>>>(esrc, edst, bbase, boff, ebuf);
  k_bdeg   <<<NBK, 256, 0, stream>>>(ebuf, bbase, deg, dinv);
  k_scan1  <<<nb, 1024, 0, stream>>>(deg, offs, bsum);
  k_scan2  <<<1, 64, 0, stream>>>(bsum, offs, nb);
  k_scan3  <<<nb, 1024, 0, stream>>>(offs, bsum);
  k_fill2  <<<NBK, 256, 0, stream>>>(ebuf, bbase, offs, csr);

  k_wcombo <<<1, 256, 0, stream>>>(W1, b1, W2, b2, Wc, bc, Wcb, c12);
  k_y      <<<(NN * 8 + 255) / 256, 256, 0, stream>>>(seq, Wcb, dinv, Yp);
  k_agg1   <<<(NN * 2 + 255) / 256, 256, 0, stream>>>(csr, offs, dinv, Yp, U, V);
  k_agg2   <<<(NN * 2 + 255) / 256, 256, 0, stream>>>(csr, offs, dinv, U, V, c12, out);
}

// Round 6
// 133.198 us; speedup vs baseline: 2.0202x; 1.0798x over previous
//
#include <hip/hip_runtime.h>
#include <hip/hip_bf16.h>
#include <stdint.h>

#define NN 50000
#define NE 1600000
#define BSH 8            // bucket = 256 dst nodes
#define NBK 196          // ceil(NN/256)
#define CAP 9216         // slots per bucket (expected 8192, sigma~90)
#define NSB 512          // edge-pass blocks
#define ECH 3125         // edges per block (NSB*ECH == NE exactly)

// ---------------- phase 0: collapsed weights + gofs init ----------------
// M1 = W2@Wc [128,8]; Wcombo = W1@M1 [256,8]; c1 = M1^T b1; c2 = Wc^T b2 + bc
__global__ __launch_bounds__(256) void k_wcombo(const float* __restrict__ W1, const float* __restrict__ b1,
                                                const float* __restrict__ W2, const float* __restrict__ b2,
                                                const float* __restrict__ Wc, const float* __restrict__ bc,
                                                float* __restrict__ Wcombo, float* __restrict__ c12,
                                                int* __restrict__ gofs){
  __shared__ float M1[128 * 8];
  int t = threadIdx.x;
  if (t < NBK) gofs[t] = t * CAP;
  for (int idx = t; idx < 1024; idx += 256){
    int k = idx >> 3, c = idx & 7;
    float s = 0.f;
    for (int j = 0; j < 64; ++j) s += W2[k * 64 + j] * Wc[j * 8 + c];
    M1[idx] = s;
  }
  __syncthreads();
  for (int idx = t; idx < 2048; idx += 256){
    int i = idx >> 3, c = idx & 7;
    float s = 0.f;
    for (int k = 0; k < 128; ++k) s += W1[i * 128 + k] * M1[k * 8 + c];
    Wcombo[idx] = s;
  }
  if (t < 8){
    float s = 0.f;
    for (int k = 0; k < 128; ++k) s += b1[k] * M1[k * 8 + t];
    c12[t] = s;
  } else if (t < 16){
    int c = t - 8;
    float s = bc[c];
    for (int k = 0; k < 64; ++k) s += b2[k] * Wc[k * 8 + c];
    c12[t] = s;
  }
}

// ---------------- phase 1: per-block bucket histogram; grab base via global atomic ----------------
__global__ __launch_bounds__(256) void k_histA(const int* __restrict__ dst, int* __restrict__ gofs,
                                               int* __restrict__ boff){
  __shared__ int h[NBK];
  for (int i = threadIdx.x; i < NBK; i += 256) h[i] = 0;
  __syncthreads();
  int e0 = blockIdx.x * ECH;
  for (int e = e0 + threadIdx.x; e < e0 + ECH; e += 256)
    atomicAdd(&h[dst[e] >> BSH], 1);
  __syncthreads();
  for (int i = threadIdx.x; i < NBK; i += 256)
    boff[blockIdx.x * NBK + i] = atomicAdd(&gofs[i], h[i]);
}

// ---------------- phase 2: scatter packed (src<<16 | dst) into capacity-padded buckets ----------------
__global__ __launch_bounds__(256) void k_scat(const int* __restrict__ src, const int* __restrict__ dst,
                                              const int* __restrict__ boff, uint32_t* __restrict__ ebuf){
  __shared__ int ctr[NBK];
  for (int i = threadIdx.x; i < NBK; i += 256)
    ctr[i] = boff[blockIdx.x * NBK + i];
  __syncthreads();
  int e0 = blockIdx.x * ECH;
  for (int e = e0 + threadIdx.x; e < e0 + ECH; e += 256){
    int d = dst[e];
    int s = src[e];
    int p = atomicAdd(&ctr[d >> BSH], 1);
    ebuf[p] = ((uint32_t)s << 16) | (uint32_t)d;
  }
}

// ---------------- phase 3: per-bucket degree + scan + dinv + offs2 + csr fill ----------------
__global__ __launch_bounds__(256) void k_csr(const uint32_t* __restrict__ ebuf, const int* __restrict__ gofs,
                                             float* __restrict__ dinv, int2* __restrict__ offs2,
                                             unsigned short* __restrict__ csr){
  __shared__ int lds[256];
  const int t = threadIdx.x;
  const int b = blockIdx.x;
  const int base = b * CAP;
  const int cnt = gofs[b] - base;
  lds[t] = 0;
  __syncthreads();
  for (int e = base + t; e < base + cnt; e += 256)
    atomicAdd(&lds[ebuf[e] & 255], 1);
  __syncthreads();
  int deg = lds[t];
  for (int ofs = 1; ofs < 256; ofs <<= 1){
    int tv = (t >= ofs) ? lds[t - ofs] : 0;
    __syncthreads();
    lds[t] += tv;
    __syncthreads();
  }
  int excl = lds[t] - deg;
  int node = (b << BSH) + t;
  if (node < NN){
    dinv[node] = rsqrtf((float)(deg + 1));
    offs2[node] = make_int2(base + excl, base + excl + deg);
  }
  __syncthreads();
  lds[t] = base + excl;
  __syncthreads();
  for (int e = base + t; e < base + cnt; e += 256){
    uint32_t v = ebuf[e];
    int p = atomicAdd(&lds[v & 255], 1);
    csr[p] = (unsigned short)(v >> 16);
  }
}

// ---------------- Y' = dinv ⊙ (X @ Wcombo)  [NN, 8] ----------------
__global__ __launch_bounds__(256) void k_y(const float* __restrict__ X, const float* __restrict__ Wcombo,
                                           const float* __restrict__ dinv, float* __restrict__ Yp){
  __shared__ float Wl[2048];
  int t = threadIdx.x;
  for (int i = t; i < 2048; i += 256) Wl[i] = Wcombo[i];
  __syncthreads();
  int gid = blockIdx.x * 256 + t;
  int row = gid >> 3, c = gid & 7;
  if (row >= NN) return;
  const float* Xr = X + (size_t)row * 256;
  float acc = 0.f;
  #pragma unroll 8
  for (int k = 0; k < 256; k += 4){
    float4 x = *(const float4*)(Xr + k);
    acc += x.x * Wl[k * 8 + c] + x.y * Wl[(k + 1) * 8 + c]
         + x.z * Wl[(k + 2) * 8 + c] + x.w * Wl[(k + 3) * 8 + c];
  }
  Yp[(size_t)row * 8 + c] = acc * dinv[row];
}

// ---------------- agg pass 1: U = dinv^2*(sum_src Yp + Yp[self]); V = dinv*(sum_src dinv + dinv) ----------------
__global__ __launch_bounds__(256) void k_agg1(const unsigned short* __restrict__ csr, const int2* __restrict__ offs2,
                                              const float* __restrict__ dinv, const float* __restrict__ Yp,
                                              float* __restrict__ U, float* __restrict__ V){
  int gid = blockIdx.x * 256 + threadIdx.x;
  int node = gid >> 1, half = gid & 1;
  if (node >= NN) return;
  int2 oe = offs2[node];
  int e0 = oe.x, e1 = oe.y;
  float4 a = {0.f, 0.f, 0.f, 0.f};
  float vd = 0.f;
  int e = e0;
  for (; e + 2 <= e1; e += 2){
    int s0 = csr[e], s1 = csr[e + 1];
    float4 y0 = *(const float4*)(Yp + (size_t)s0 * 8 + half * 4);
    float4 y1 = *(const float4*)(Yp + (size_t)s1 * 8 + half * 4);
    a.x += y0.x + y1.x; a.y += y0.y + y1.y;
    a.z += y0.z + y1.z; a.w += y0.w + y1.w;
    if (half == 0) vd += dinv[s0] + dinv[s1];
  }
  if (e < e1){
    int s0 = csr[e];
    float4 y0 = *(const float4*)(Yp + (size_t)s0 * 8 + half * 4);
    a.x += y0.x; a.y += y0.y; a.z += y0.z; a.w += y0.w;
    if (half == 0) vd += dinv[s0];
  }
  float di = dinv[node];
  float4 self = *(const float4*)(Yp + (size_t)node * 8 + half * 4);
  float s2 = di * di;
  float4 o;
  o.x = s2 * (a.x + self.x); o.y = s2 * (a.y + self.y);
  o.z = s2 * (a.z + self.z); o.w = s2 * (a.w + self.w);
  *(float4*)(U + (size_t)node * 8 + half * 4) = o;
  if (half == 0) V[node] = di * (vd + di);
}

// ---------------- agg pass 2: out = dinv*(sum_src U + U[self]) + V*c1 + c2 ----------------
__global__ __launch_bounds__(256) void k_agg2(const unsigned short* __restrict__ csr, const int2* __restrict__ offs2,
                                              const float* __restrict__ dinv, const float* __restrict__ U,
                                              const float* __restrict__ V, const float* __restrict__ c12,
                                              float* __restrict__ O){
  int gid = blockIdx.x * 256 + threadIdx.x;
  int node = gid >> 1, half = gid & 1;
  if (node >= NN) return;
  int2 oe = offs2[node];
  int e0 = oe.x, e1 = oe.y;
  float4 a = {0.f, 0.f, 0.f, 0.f};
  int e = e0;
  for (; e + 2 <= e1; e += 2){
    int s0 = csr[e], s1 = csr[e + 1];
    float4 y0 = *(const float4*)(U + (size_t)s0 * 8 + half * 4);
    float4 y1 = *(const float4*)(U + (size_t)s1 * 8 + half * 4);
    a.x += y0.x + y1.x; a.y += y0.y + y1.y;
    a.z += y0.z + y1.z; a.w += y0.w + y1.w;
  }
  if (e < e1){
    int s0 = csr[e];
    float4 y0 = *(const float4*)(U + (size_t)s0 * 8 + half * 4);
    a.x += y0.x; a.y += y0.y; a.z += y0.z; a.w += y0.w;
  }
  float di = dinv[node];
  float4 self = *(const float4*)(U + (size_t)node * 8 + half * 4);
  float4 c1 = *(const float4*)(c12 + half * 4);
  float4 c2 = *(const float4*)(c12 + 8 + half * 4);
  float vn = V[node];
  float4 o;
  o.x = di * (a.x + self.x) + vn * c1.x + c2.x;
  o.y = di * (a.y + self.y) + vn * c1.y + c2.y;
  o.z = di * (a.z + self.z) + vn * c1.z + c2.z;
  o.w = di * (a.w + self.w) + vn * c1.w + c2.w;
  *(float4*)(O + (size_t)node * 8 + half * 4) = o;
}

extern "C" void kernel_launch(void* const* d_in, const int* in_sizes, int n_in,
                              void* d_out, int out_size, void* d_ws, size_t ws_size,
                              hipStream_t stream) {
  const float* seq = (const float*)d_in[0];
  const int*   ei  = (const int*)d_in[1];
  const int*   esrc = ei;
  const int*   edst = ei + NE;
  const float* W1 = (const float*)d_in[2];
  const float* b1 = (const float*)d_in[3];
  const float* W2 = (const float*)d_in[4];
  const float* b2 = (const float*)d_in[5];
  const float* Wc = (const float*)d_in[6];
  const float* bc = (const float*)d_in[7];
  float* out = (float*)d_out;

  char* ws = (char*)d_ws;
  size_t o = 0;
  auto alloc = [&](size_t bytes) -> void* {
    void* p = ws + o;
    o += (bytes + 255) & ~(size_t)255;
    return p;
  };
  int*      gofs  = (int*)alloc((size_t)NBK * 4);
  int*      boff  = (int*)alloc((size_t)NSB * NBK * 4);
  uint32_t* ebuf  = (uint32_t*)alloc((size_t)NBK * CAP * 4);
  unsigned short* csr = (unsigned short*)alloc((size_t)NBK * CAP * 2);
  int2*     offs2 = (int2*)alloc((size_t)NN * 8);
  float*    dinv  = (float*)alloc((size_t)NN * 4);
  float*    Wcb   = (float*)alloc(2048 * 4);
  float*    c12   = (float*)alloc(16 * 4);
  float*    Yp    = (float*)alloc((size_t)NN * 8 * 4);
  float*    U     = (float*)alloc((size_t)NN * 8 * 4);
  float*    V     = (float*)alloc((size_t)NN * 4);

  k_wcombo <<<1, 256, 0, stream>>>(W1, b1, W2, b2, Wc, bc, Wcb, c12, gofs);
  k_histA  <<<NSB, 256, 0, stream>>>(edst, gofs, boff);
  k_scat   <<<NSB, 256, 0, stream>>>(esrc, edst, boff, ebuf);
  k_csr    <<<NBK, 256, 0, stream>>>(ebuf, gofs, dinv, offs2, csr);
  k_y      <<<(NN * 8 + 255) / 256, 256, 0, stream>>>(seq, Wcb, dinv, Yp);
  k_agg1   <<<(NN * 2 + 255) / 256, 256, 0, stream>>>(csr, offs2, dinv, Yp, U, V);
  k_agg2   <<<(NN * 2 + 255) / 256, 256, 0, stream>>>(csr, offs2, dinv, U, V, c12, out);
}

// Round 7
// 122.795 us; speedup vs baseline: 2.1913x; 1.0847x over previous
//
#include <hip/hip_runtime.h>
#include <hip/hip_bf16.h>
#include <stdint.h>

#define NN 50000
#define NE 1600000
#define BSH 7            // bucket = 128 dst nodes
#define NBK 391          // ceil(NN/128)
#define CAP 4608         // slots per bucket (mean 4096, sigma~64, +8 sigma)
#define NSB 640          // edge-pass blocks
#define ECH 2500         // edges per block (NSB*ECH == NE exactly)

// ---------------- phase 0: collapsed weights + gofs init ----------------
// M1 = W2@Wc [128,8]; Wcombo = W1@M1 [256,8]; c1 = M1^T b1; c2 = Wc^T b2 + bc
__global__ __launch_bounds__(256) void k_wcombo(const float* __restrict__ W1, const float* __restrict__ b1,
                                                const float* __restrict__ W2, const float* __restrict__ b2,
                                                const float* __restrict__ Wc, const float* __restrict__ bc,
                                                float* __restrict__ Wcombo, float* __restrict__ c12,
                                                int* __restrict__ gofs){
  __shared__ float M1[128 * 8];
  int t = threadIdx.x;
  for (int i = t; i < NBK; i += 256) gofs[i] = i * CAP;
  for (int idx = t; idx < 1024; idx += 256){
    int k = idx >> 3, c = idx & 7;
    float s = 0.f;
    for (int j = 0; j < 64; ++j) s += W2[k * 64 + j] * Wc[j * 8 + c];
    M1[idx] = s;
  }
  __syncthreads();
  for (int idx = t; idx < 2048; idx += 256){
    int i = idx >> 3, c = idx & 7;
    float s = 0.f;
    for (int k = 0; k < 128; ++k) s += W1[i * 128 + k] * M1[k * 8 + c];
    Wcombo[idx] = s;
  }
  if (t < 8){
    float s = 0.f;
    for (int k = 0; k < 128; ++k) s += b1[k] * M1[k * 8 + t];
    c12[t] = s;
  } else if (t < 16){
    int c = t - 8;
    float s = bc[c];
    for (int k = 0; k < 64; ++k) s += b2[k] * Wc[k * 8 + c];
    c12[t] = s;
  }
}

// ---------------- phase 1: fused histogram + base-grab + scatter ----------------
__global__ __launch_bounds__(256) void k_hs(const int* __restrict__ src, const int* __restrict__ dst,
                                            int* __restrict__ gofs, uint32_t* __restrict__ ebuf){
  __shared__ int h[NBK];
  for (int i = threadIdx.x; i < NBK; i += 256) h[i] = 0;
  __syncthreads();
  const int e0 = blockIdx.x * ECH;
  for (int e = e0 + threadIdx.x; e < e0 + ECH; e += 256)
    atomicAdd(&h[dst[e] >> BSH], 1);
  __syncthreads();
  for (int i = threadIdx.x; i < NBK; i += 256)
    h[i] = atomicAdd(&gofs[i], h[i]);          // h becomes this block's running base
  __syncthreads();
  for (int e = e0 + threadIdx.x; e < e0 + ECH; e += 256){
    int d = dst[e];
    int s = src[e];
    int p = atomicAdd(&h[d >> BSH], 1);
    ebuf[p] = ((uint32_t)s << 16) | (uint32_t)d;
  }
}

// ---------------- phase 2: per-bucket degree + scan + dinv + offs2 + csr fill ----------------
__global__ __launch_bounds__(256) void k_csr(const uint32_t* __restrict__ ebuf, const int* __restrict__ gofs,
                                             float* __restrict__ dinv, int2* __restrict__ offs2,
                                             unsigned short* __restrict__ csr){
  __shared__ int lds[128];
  const int t = threadIdx.x;
  const int b = blockIdx.x;
  const int base = b * CAP;
  const int cnt = gofs[b] - base;
  if (t < 128) lds[t] = 0;
  __syncthreads();
  for (int e = base + t; e < base + cnt; e += 256)
    atomicAdd(&lds[ebuf[e] & 127], 1);
  __syncthreads();
  int deg = (t < 128) ? lds[t] : 0;
  for (int ofs = 1; ofs < 128; ofs <<= 1){
    int tv = (t >= ofs && t < 128) ? lds[t - ofs] : 0;
    __syncthreads();
    if (t < 128) lds[t] += tv;
    __syncthreads();
  }
  int startp = base + ((t < 128) ? lds[t] : 0) - deg;
  int node = (b << BSH) + t;
  if (t < 128 && node < NN){
    dinv[node] = rsqrtf((float)(deg + 1));
    offs2[node] = make_int2(startp, startp + deg);
  }
  __syncthreads();
  if (t < 128) lds[t] = startp;
  __syncthreads();
  for (int e = base + t; e < base + cnt; e += 256){
    uint32_t v = ebuf[e];
    int p = atomicAdd(&lds[v & 127], 1);
    csr[p] = (unsigned short)(v >> 16);
  }
}

// ---------------- Y' = dinv ⊙ (X @ Wcombo)  [NN, 8] ----------------
__global__ __launch_bounds__(256) void k_y(const float* __restrict__ X, const float* __restrict__ Wcombo,
                                           const float* __restrict__ dinv, float* __restrict__ Yp){
  __shared__ float Wl[2048];
  int t = threadIdx.x;
  for (int i = t; i < 2048; i += 256) Wl[i] = Wcombo[i];
  __syncthreads();
  int gid = blockIdx.x * 256 + t;
  int row = gid >> 3, c = gid & 7;
  if (row >= NN) return;
  const float* Xr = X + (size_t)row * 256;
  float acc = 0.f;
  #pragma unroll 8
  for (int k = 0; k < 256; k += 4){
    float4 x = *(const float4*)(Xr + k);
    acc += x.x * Wl[k * 8 + c] + x.y * Wl[(k + 1) * 8 + c]
         + x.z * Wl[(k + 2) * 8 + c] + x.w * Wl[(k + 3) * 8 + c];
  }
  Yp[(size_t)row * 8 + c] = acc * dinv[row];
}

// ---------------- agg pass 1: 8 lanes per node ----------------
// U = dinv^2*(sum_src Yp + Yp[self]);  V = dinv*(sum_src dinv + dinv)   (lane 0)
__global__ __launch_bounds__(256) void k_agg1(const unsigned short* __restrict__ csr, const int2* __restrict__ offs2,
                                              const float* __restrict__ dinv, const float* __restrict__ Yp,
                                              float* __restrict__ U, float* __restrict__ V){
  int gid = blockIdx.x * 256 + threadIdx.x;
  int node = gid >> 3, c = gid & 7;
  if (node >= NN) return;
  int2 oe = offs2[node];
  int e = oe.x;
  const int e1 = oe.y;
  float a = 0.f, vd = 0.f;
  for (; e + 4 <= e1; e += 4){
    int s0 = csr[e], s1 = csr[e + 1], s2 = csr[e + 2], s3 = csr[e + 3];
    float y0 = Yp[(size_t)s0 * 8 + c], y1 = Yp[(size_t)s1 * 8 + c];
    float y2 = Yp[(size_t)s2 * 8 + c], y3 = Yp[(size_t)s3 * 8 + c];
    a += (y0 + y1) + (y2 + y3);
    if (c == 0) vd += (dinv[s0] + dinv[s1]) + (dinv[s2] + dinv[s3]);
  }
  for (; e < e1; ++e){
    int s0 = csr[e];
    a += Yp[(size_t)s0 * 8 + c];
    if (c == 0) vd += dinv[s0];
  }
  float di = dinv[node];
  U[(size_t)node * 8 + c] = di * di * (a + Yp[(size_t)node * 8 + c]);
  if (c == 0) V[node] = di * (vd + di);
}

// ---------------- agg pass 2: out = dinv*(sum_src U + U[self]) + V*c1 + c2 ----------------
__global__ __launch_bounds__(256) void k_agg2(const unsigned short* __restrict__ csr, const int2* __restrict__ offs2,
                                              const float* __restrict__ dinv, const float* __restrict__ U,
                                              const float* __restrict__ V, const float* __restrict__ c12,
                                              float* __restrict__ O){
  int gid = blockIdx.x * 256 + threadIdx.x;
  int node = gid >> 3, c = gid & 7;
  if (node >= NN) return;
  int2 oe = offs2[node];
  int e = oe.x;
  const int e1 = oe.y;
  float a = 0.f;
  for (; e + 4 <= e1; e += 4){
    int s0 = csr[e], s1 = csr[e + 1], s2 = csr[e + 2], s3 = csr[e + 3];
    float y0 = U[(size_t)s0 * 8 + c], y1 = U[(size_t)s1 * 8 + c];
    float y2 = U[(size_t)s2 * 8 + c], y3 = U[(size_t)s3 * 8 + c];
    a += (y0 + y1) + (y2 + y3);
  }
  for (; e < e1; ++e){
    int s0 = csr[e];
    a += U[(size_t)s0 * 8 + c];
  }
  float di = dinv[node];
  O[(size_t)node * 8 + c] = di * (a + U[(size_t)node * 8 + c]) + V[node] * c12[c] + c12[8 + c];
}

extern "C" void kernel_launch(void* const* d_in, const int* in_sizes, int n_in,
                              void* d_out, int out_size, void* d_ws, size_t ws_size,
                              hipStream_t stream) {
  const float* seq = (const float*)d_in[0];
  const int*   ei  = (const int*)d_in[1];
  const int*   esrc = ei;
  const int*   edst = ei + NE;
  const float* W1 = (const float*)d_in[2];
  const float* b1 = (const float*)d_in[3];
  const float* W2 = (const float*)d_in[4];
  const float* b2 = (const float*)d_in[5];
  const float* Wc = (const float*)d_in[6];
  const float* bc = (const float*)d_in[7];
  float* out = (float*)d_out;

  char* ws = (char*)d_ws;
  size_t o = 0;
  auto alloc = [&](size_t bytes) -> void* {
    void* p = ws + o;
    o += (bytes + 255) & ~(size_t)255;
    return p;
  };
  int*      gofs  = (int*)alloc((size_t)NBK * 4);
  uint32_t* ebuf  = (uint32_t*)alloc((size_t)NBK * CAP * 4);
  unsigned short* csr = (unsigned short*)alloc((size_t)NBK * CAP * 2);
  int2*     offs2 = (int2*)alloc((size_t)NN * 8);
  float*    dinv  = (float*)alloc((size_t)NN * 4);
  float*    Wcb   = (float*)alloc(2048 * 4);
  float*    c12   = (float*)alloc(16 * 4);
  float*    Yp    = (float*)alloc((size_t)NN * 8 * 4);
  float*    U     = (float*)alloc((size_t)NN * 8 * 4);
  float*    V     = (float*)alloc((size_t)NN * 4);

  k_wcombo <<<1, 256, 0, stream>>>(W1, b1, W2, b2, Wc, bc, Wcb, c12, gofs);
  k_hs     <<<NSB, 256, 0, stream>>>(esrc, edst, gofs, ebuf);
  k_csr    <<<NBK, 256, 0, stream>>>(ebuf, gofs, dinv, offs2, csr);
  k_y      <<<(NN * 8 + 255) / 256, 256, 0, stream>>>(seq, Wcb, dinv, Yp);
  k_agg1   <<<(NN * 8 + 255) / 256, 256, 0, stream>>>(csr, offs2, dinv, Yp, U, V);
  k_agg2   <<<(NN * 8 + 255) / 256, 256, 0, stream>>>(csr, offs2, dinv, U, V, c12, out);
}

// Round 8
// 120.874 us; speedup vs baseline: 2.2261x; 1.0159x over previous
//
#include <hip/hip_runtime.h>
#include <hip/hip_bf16.h>
#include <stdint.h>

#define NN 50000
#define NE 1600000
#define BSH 7            // bucket = 128 dst nodes
#define NBK 391          // ceil(NN/128)
#define CAP 4608         // slots per bucket (mean 4092, sigma~64, +8 sigma)
#define NSB 1024         // edge-pass blocks
#define ECH 1563         // edges per block (NSB*ECH >= NE, last block short)

// ---------------- phase 0: collapsed weights ----------------
// M1 = W2@Wc [128,8]; Wcombo = W1@M1 [256,8]; c1 = M1^T b1; c2 = Wc^T b2 + bc
__global__ __launch_bounds__(256) void k_wcombo(const float* __restrict__ W1, const float* __restrict__ b1,
                                                const float* __restrict__ W2, const float* __restrict__ b2,
                                                const float* __restrict__ Wc, const float* __restrict__ bc,
                                                float* __restrict__ Wcombo, float* __restrict__ c12){
  __shared__ float M1[128 * 8];
  int t = threadIdx.x;
  for (int idx = t; idx < 1024; idx += 256){
    int k = idx >> 3, c = idx & 7;
    float s = 0.f;
    for (int j = 0; j < 64; ++j) s += W2[k * 64 + j] * Wc[j * 8 + c];
    M1[idx] = s;
  }
  __syncthreads();
  for (int idx = t; idx < 2048; idx += 256){
    int i = idx >> 3, c = idx & 7;
    float s = 0.f;
    for (int k = 0; k < 128; ++k) s += W1[i * 128 + k] * M1[k * 8 + c];
    Wcombo[idx] = s;
  }
  if (t < 8){
    float s = 0.f;
    for (int k = 0; k < 128; ++k) s += b1[k] * M1[k * 8 + t];
    c12[t] = s;
  } else if (t < 16){
    int c = t - 8;
    float s = bc[c];
    for (int k = 0; k < 64; ++k) s += b2[k] * Wc[k * 8 + c];
    c12[t] = s;
  }
}

// ---------------- phase 1: per-block bucket histogram (per-wave split copies) ----------------
__global__ __launch_bounds__(256) void k_hist(const int* __restrict__ dst, int* __restrict__ bh){
  __shared__ int h[4 * NBK];
  for (int i = threadIdx.x; i < 4 * NBK; i += 256) h[i] = 0;
  __syncthreads();
  const int wv = (threadIdx.x >> 6) * NBK;
  const int e0 = blockIdx.x * ECH;
  const int e1 = (e0 + ECH < NE) ? e0 + ECH : NE;
  for (int e = e0 + threadIdx.x; e < e1; e += 256)
    atomicAdd(&h[wv + (dst[e] >> BSH)], 1);
  __syncthreads();
  for (int i = threadIdx.x; i < NBK; i += 256)
    bh[(size_t)blockIdx.x * NBK + i] = h[i] + h[NBK + i] + h[2 * NBK + i] + h[3 * NBK + i];
}

// ---------------- phase 2: per-bucket exclusive scan over the NSB blocks ----------------
__global__ __launch_bounds__(1024) void k_bscan(const int* __restrict__ bh, int* __restrict__ boff,
                                                int* __restrict__ btot){
  __shared__ int lds[NSB];
  const int b = blockIdx.x;
  int v = bh[(size_t)threadIdx.x * NBK + b];
  lds[threadIdx.x] = v;
  __syncthreads();
  for (int ofs = 1; ofs < NSB; ofs <<= 1){
    int t = (threadIdx.x >= ofs) ? lds[threadIdx.x - ofs] : 0;
    __syncthreads();
    lds[threadIdx.x] += t;
    __syncthreads();
  }
  boff[(size_t)threadIdx.x * NBK + b] = lds[threadIdx.x] - v;
  if (threadIdx.x == NSB - 1) btot[b] = lds[NSB - 1];
}

// ---------------- phase 3: scatter packed (src<<16 | dst) into capacity-padded buckets ----------------
__global__ __launch_bounds__(256) void k_scat(const int* __restrict__ src, const int* __restrict__ dst,
                                              const int* __restrict__ boff, uint32_t* __restrict__ ebuf){
  __shared__ int ctr[NBK];
  for (int i = threadIdx.x; i < NBK; i += 256)
    ctr[i] = i * CAP + boff[(size_t)blockIdx.x * NBK + i];
  __syncthreads();
  const int e0 = blockIdx.x * ECH;
  const int e1 = (e0 + ECH < NE) ? e0 + ECH : NE;
  for (int e = e0 + threadIdx.x; e < e1; e += 256){
    int d = dst[e];
    int s = src[e];
    int p = atomicAdd(&ctr[d >> BSH], 1);
    ebuf[p] = ((uint32_t)s << 16) | (uint32_t)d;
  }
}

// ---------------- phase 4: per-bucket LDS-staged degree + scan + dinv + offs2 + csr ----------------
__global__ __launch_bounds__(256) void k_csr(const uint32_t* __restrict__ ebuf, const int* __restrict__ btot,
                                             float* __restrict__ dinv, int2* __restrict__ offs2,
                                             unsigned short* __restrict__ csr){
  __shared__ uint32_t lede[CAP];
  __shared__ unsigned short lcsr[CAP];
  __shared__ int h[128];
  __shared__ int sb[128];
  const int t = threadIdx.x;
  const int b = blockIdx.x;
  const int base = b * CAP;
  const int cnt = btot[b];
  for (int i = t; i < cnt; i += 256) lede[i] = ebuf[base + i];
  if (t < 128) h[t] = 0;
  __syncthreads();
  for (int i = t; i < cnt; i += 256)
    atomicAdd(&h[lede[i] & 127], 1);
  __syncthreads();
  int deg = (t < 128) ? h[t] : 0;
  for (int ofs = 1; ofs < 128; ofs <<= 1){
    int tv = (t >= ofs && t < 128) ? h[t - ofs] : 0;
    __syncthreads();
    if (t < 128) h[t] += tv;
    __syncthreads();
  }
  int excl = (t < 128) ? (h[t] - deg) : 0;
  int node = (b << BSH) + t;
  if (t < 128 && node < NN){
    dinv[node] = rsqrtf((float)(deg + 1));
    offs2[node] = make_int2(base + excl, base + excl + deg);
  }
  __syncthreads();
  if (t < 128) sb[t] = excl;
  __syncthreads();
  for (int i = t; i < cnt; i += 256){
    uint32_t v = lede[i];
    int p = atomicAdd(&sb[v & 127], 1);
    lcsr[p] = (unsigned short)(v >> 16);
  }
  __syncthreads();
  // coalesced copy-out (4B granules; trailing pad slot within bucket capacity is harmless)
  uint32_t* dstw = (uint32_t*)(csr + base);
  const uint32_t* srcw = (const uint32_t*)lcsr;
  int nw = (cnt + 1) >> 1;
  for (int i = t; i < nw; i += 256) dstw[i] = srcw[i];
}

// ---------------- Y' = dinv ⊙ (X @ Wcombo)  [NN, 8] ----------------
__global__ __launch_bounds__(256) void k_y(const float* __restrict__ X, const float* __restrict__ Wcombo,
                                           const float* __restrict__ dinv, float* __restrict__ Yp){
  __shared__ float Wl[2048];
  int t = threadIdx.x;
  for (int i = t; i < 2048; i += 256) Wl[i] = Wcombo[i];
  __syncthreads();
  int gid = blockIdx.x * 256 + t;
  int row = gid >> 3, c = gid & 7;
  if (row >= NN) return;
  const float* Xr = X + (size_t)row * 256;
  float acc = 0.f;
  #pragma unroll 8
  for (int k = 0; k < 256; k += 4){
    float4 x = *(const float4*)(Xr + k);
    acc += x.x * Wl[k * 8 + c] + x.y * Wl[(k + 1) * 8 + c]
         + x.z * Wl[(k + 2) * 8 + c] + x.w * Wl[(k + 3) * 8 + c];
  }
  Yp[(size_t)row * 8 + c] = acc * dinv[row];
}

// ---------------- agg pass 1: 8 lanes per node ----------------
// U = dinv^2*(sum_src Yp + Yp[self]);  V = dinv*(sum_src dinv + dinv)   (lane 0)
__global__ __launch_bounds__(256) void k_agg1(const unsigned short* __restrict__ csr, const int2* __restrict__ offs2,
                                              const float* __restrict__ dinv, const float* __restrict__ Yp,
                                              float* __restrict__ U, float* __restrict__ V){
  int gid = blockIdx.x * 256 + threadIdx.x;
  int node = gid >> 3, c = gid & 7;
  if (node >= NN) return;
  int2 oe = offs2[node];
  int e = oe.x;
  const int e1 = oe.y;
  float a = 0.f, vd = 0.f;
  for (; e + 4 <= e1; e += 4){
    int s0 = csr[e], s1 = csr[e + 1], s2 = csr[e + 2], s3 = csr[e + 3];
    float y0 = Yp[(size_t)s0 * 8 + c], y1 = Yp[(size_t)s1 * 8 + c];
    float y2 = Yp[(size_t)s2 * 8 + c], y3 = Yp[(size_t)s3 * 8 + c];
    a += (y0 + y1) + (y2 + y3);
    if (c == 0) vd += (dinv[s0] + dinv[s1]) + (dinv[s2] + dinv[s3]);
  }
  for (; e < e1; ++e){
    int s0 = csr[e];
    a += Yp[(size_t)s0 * 8 + c];
    if (c == 0) vd += dinv[s0];
  }
  float di = dinv[node];
  U[(size_t)node * 8 + c] = di * di * (a + Yp[(size_t)node * 8 + c]);
  if (c == 0) V[node] = di * (vd + di);
}

// ---------------- agg pass 2: out = dinv*(sum_src U + U[self]) + V*c1 + c2 ----------------
__global__ __launch_bounds__(256) void k_agg2(const unsigned short* __restrict__ csr, const int2* __restrict__ offs2,
                                              const float* __restrict__ dinv, const float* __restrict__ U,
                                              const float* __restrict__ V, const float* __restrict__ c12,
                                              float* __restrict__ O){
  int gid = blockIdx.x * 256 + threadIdx.x;
  int node = gid >> 3, c = gid & 7;
  if (node >= NN) return;
  int2 oe = offs2[node];
  int e = oe.x;
  const int e1 = oe.y;
  float a = 0.f;
  for (; e + 4 <= e1; e += 4){
    int s0 = csr[e], s1 = csr[e + 1], s2 = csr[e + 2], s3 = csr[e + 3];
    float y0 = U[(size_t)s0 * 8 + c], y1 = U[(size_t)s1 * 8 + c];
    float y2 = U[(size_t)s2 * 8 + c], y3 = U[(size_t)s3 * 8 + c];
    a += (y0 + y1) + (y2 + y3);
  }
  for (; e < e1; ++e){
    int s0 = csr[e];
    a += U[(size_t)s0 * 8 + c];
  }
  float di = dinv[node];
  O[(size_t)node * 8 + c] = di * (a + U[(size_t)node * 8 + c]) + V[node] * c12[c] + c12[8 + c];
}

extern "C" void kernel_launch(void* const* d_in, const int* in_sizes, int n_in,
                              void* d_out, int out_size, void* d_ws, size_t ws_size,
                              hipStream_t stream) {
  const float* seq = (const float*)d_in[0];
  const int*   ei  = (const int*)d_in[1];
  const int*   esrc = ei;
  const int*   edst = ei + NE;
  const float* W1 = (const float*)d_in[2];
  const float* b1 = (const float*)d_in[3];
  const float* W2 = (const float*)d_in[4];
  const float* b2 = (const float*)d_in[5];
  const float* Wc = (const float*)d_in[6];
  const float* bc = (const float*)d_in[7];
  float* out = (float*)d_out;

  char* ws = (char*)d_ws;
  size_t o = 0;
  auto alloc = [&](size_t bytes) -> void* {
    void* p = ws + o;
    o += (bytes + 255) & ~(size_t)255;
    return p;
  };
  int*      bh    = (int*)alloc((size_t)NSB * NBK * 4);
  int*      boff  = (int*)alloc((size_t)NSB * NBK * 4);
  int*      btot  = (int*)alloc((size_t)NBK * 4);
  uint32_t* ebuf  = (uint32_t*)alloc((size_t)NBK * CAP * 4);
  unsigned short* csr = (unsigned short*)alloc((size_t)NBK * CAP * 2);
  int2*     offs2 = (int2*)alloc((size_t)NN * 8);
  float*    dinv  = (float*)alloc((size_t)NN * 4);
  float*    Wcb   = (float*)alloc(2048 * 4);
  float*    c12   = (float*)alloc(16 * 4);
  float*    Yp    = (float*)alloc((size_t)NN * 8 * 4);
  float*    U     = (float*)alloc((size_t)NN * 8 * 4);
  float*    V     = (float*)alloc((size_t)NN * 4);

  k_wcombo <<<1, 256, 0, stream>>>(W1, b1, W2, b2, Wc, bc, Wcb, c12);
  k_hist   <<<NSB, 256, 0, stream>>>(edst, bh);
  k_bscan  <<<NBK, NSB, 0, stream>>>(bh, boff, btot);
  k_scat   <<<NSB, 256, 0, stream>>>(esrc, edst, boff, ebuf);
  k_csr    <<<NBK, 256, 0, stream>>>(ebuf, btot, dinv, offs2, csr);
  k_y      <<<(NN * 8 + 255) / 256, 256, 0, stream>>>(seq, Wcb, dinv, Yp);
  k_agg1   <<<(NN * 8 + 255) / 256, 256, 0, stream>>>(csr, offs2, dinv, Yp, U, V);
  k_agg2   <<<(NN * 8 + 255) / 256, 256, 0, stream>>>(csr, offs2, dinv, U, V, c12, out);
}

// Round 9
// 99.254 us; speedup vs baseline: 2.7111x; 1.2178x over previous
//
#include <hip/hip_runtime.h>
#include <hip/hip_bf16.h>
#include <stdint.h>

#define NN 50000
#define NE 1600000
#define BSH 7            // bucket = 128 dst nodes
#define NBK 391          // ceil(NN/128)
#define CAP 4608         // slots per bucket (mean 4092, sigma~64, +8 sigma)
#define NSB 256          // edge-pass blocks
#define ECH 6250         // edges per block (NSB*ECH == NE exactly)

// ---------------- phase 0: collapsed weights (9 blocks) ----------------
// M1 = W2@Wc [128,8] (recomputed per block); Wcombo = W1@M1 [256,8]; c1 = M1^T b1; c2 = Wc^T b2 + bc
__global__ __launch_bounds__(256) void k_wcombo(const float* __restrict__ W1, const float* __restrict__ b1,
                                                const float* __restrict__ W2, const float* __restrict__ b2,
                                                const float* __restrict__ Wc, const float* __restrict__ bc,
                                                float* __restrict__ Wcombo, float* __restrict__ c12){
  __shared__ float M1[128 * 8];
  int t = threadIdx.x;
  for (int idx = t; idx < 1024; idx += 256){
    int k = idx >> 3, c = idx & 7;
    float s = 0.f;
    for (int j = 0; j < 64; ++j) s += W2[k * 64 + j] * Wc[j * 8 + c];
    M1[idx] = s;
  }
  __syncthreads();
  if (blockIdx.x < 8){
    // 32 rows of Wcombo per block: 32*8 = 256 outputs, one per thread
    int i = blockIdx.x * 32 + (t >> 3), c = t & 7;
    float s = 0.f;
    for (int k = 0; k < 128; ++k) s += W1[i * 128 + k] * M1[k * 8 + c];
    Wcombo[i * 8 + c] = s;
  } else {
    if (t < 8){
      float s = 0.f;
      for (int k = 0; k < 128; ++k) s += b1[k] * M1[k * 8 + t];
      c12[t] = s;
    } else if (t < 16){
      int c = t - 8;
      float s = bc[c];
      for (int k = 0; k < 64; ++k) s += b2[k] * Wc[k * 8 + c];
      c12[t] = s;
    }
  }
}

// ---------------- phase 1: per-block bucket histogram (4-way split LDS) ----------------
__global__ __launch_bounds__(256) void k_hist(const int* __restrict__ dst, int* __restrict__ bh){
  __shared__ int h[4 * NBK];
  for (int i = threadIdx.x; i < 4 * NBK; i += 256) h[i] = 0;
  __syncthreads();
  const int wv = (threadIdx.x >> 6) * NBK;
  const int e0 = blockIdx.x * ECH;
  for (int e = e0 + threadIdx.x; e < e0 + ECH; e += 256)
    atomicAdd(&h[wv + (dst[e] >> BSH)], 1);
  __syncthreads();
  for (int i = threadIdx.x; i < NBK; i += 256)
    bh[(size_t)blockIdx.x * NBK + i] = h[i] + h[NBK + i] + h[2 * NBK + i] + h[3 * NBK + i];
}

// ---------------- phase 2: per-bucket exclusive scan over the NSB blocks ----------------
__global__ __launch_bounds__(NSB) void k_bscan(const int* __restrict__ bh, int* __restrict__ boff,
                                               int* __restrict__ btot){
  __shared__ int lds[NSB];
  const int b = blockIdx.x;
  int v = bh[(size_t)threadIdx.x * NBK + b];
  lds[threadIdx.x] = v;
  __syncthreads();
  for (int ofs = 1; ofs < NSB; ofs <<= 1){
    int t = (threadIdx.x >= ofs) ? lds[threadIdx.x - ofs] : 0;
    __syncthreads();
    lds[threadIdx.x] += t;
    __syncthreads();
  }
  boff[(size_t)threadIdx.x * NBK + b] = lds[threadIdx.x] - v;
  if (threadIdx.x == NSB - 1) btot[b] = lds[NSB - 1];
}

// ---------------- phase 3: scatter packed (src<<16 | dst); ~16 edges/bucket/block => line-local writes ----------------
__global__ __launch_bounds__(256) void k_scat(const int* __restrict__ src, const int* __restrict__ dst,
                                              const int* __restrict__ boff, uint32_t* __restrict__ ebuf){
  __shared__ int ctr[NBK];
  for (int i = threadIdx.x; i < NBK; i += 256)
    ctr[i] = i * CAP + boff[(size_t)blockIdx.x * NBK + i];
  __syncthreads();
  const int e0 = blockIdx.x * ECH;
  for (int e = e0 + threadIdx.x; e < e0 + ECH; e += 256){
    int d = dst[e];
    int s = src[e];
    int p = atomicAdd(&ctr[d >> BSH], 1);
    ebuf[p] = ((uint32_t)s << 16) | (uint32_t)d;
  }
}

// ---------------- phase 4: per-bucket LDS-staged degree + scan + dinv + offs2 + csr ----------------
__global__ __launch_bounds__(256) void k_csr(const uint32_t* __restrict__ ebuf, const int* __restrict__ btot,
                                             float* __restrict__ dinv, int2* __restrict__ offs2,
                                             unsigned short* __restrict__ csr){
  __shared__ uint32_t lede[CAP];
  __shared__ unsigned short lcsr[CAP];
  __shared__ int h[128];
  __shared__ int sb[128];
  const int t = threadIdx.x;
  const int b = blockIdx.x;
  const int base = b * CAP;
  const int cnt = btot[b];
  for (int i = t; i < cnt; i += 256) lede[i] = ebuf[base + i];
  if (t < 128) h[t] = 0;
  __syncthreads();
  for (int i = t; i < cnt; i += 256)
    atomicAdd(&h[lede[i] & 127], 1);
  __syncthreads();
  int deg = (t < 128) ? h[t] : 0;
  for (int ofs = 1; ofs < 128; ofs <<= 1){
    int tv = (t >= ofs && t < 128) ? h[t - ofs] : 0;
    __syncthreads();
    if (t < 128) h[t] += tv;
    __syncthreads();
  }
  int excl = (t < 128) ? (h[t] - deg) : 0;
  int node = (b << BSH) + t;
  if (t < 128 && node < NN){
    dinv[node] = rsqrtf((float)(deg + 1));
    offs2[node] = make_int2(base + excl, base + excl + deg);
  }
  __syncthreads();
  if (t < 128) sb[t] = excl;
  __syncthreads();
  for (int i = t; i < cnt; i += 256){
    uint32_t v = lede[i];
    int p = atomicAdd(&sb[v & 127], 1);
    lcsr[p] = (unsigned short)(v >> 16);
  }
  __syncthreads();
  uint32_t* dstw = (uint32_t*)(csr + base);
  const uint32_t* srcw = (const uint32_t*)lcsr;
  int nw = (cnt + 1) >> 1;
  for (int i = t; i < nw; i += 256) dstw[i] = srcw[i];
}

// ---------------- Y' = dinv ⊙ (X @ Wcombo)  [NN, 8] ----------------
__global__ __launch_bounds__(256) void k_y(const float* __restrict__ X, const float* __restrict__ Wcombo,
                                           const float* __restrict__ dinv, float* __restrict__ Yp){
  __shared__ float Wl[2048];
  int t = threadIdx.x;
  for (int i = t; i < 2048; i += 256) Wl[i] = Wcombo[i];
  __syncthreads();
  int gid = blockIdx.x * 256 + t;
  int row = gid >> 3, c = gid & 7;
  if (row >= NN) return;
  const float* Xr = X + (size_t)row * 256;
  float acc = 0.f;
  #pragma unroll 8
  for (int k = 0; k < 256; k += 4){
    float4 x = *(const float4*)(Xr + k);
    acc += x.x * Wl[k * 8 + c] + x.y * Wl[(k + 1) * 8 + c]
         + x.z * Wl[(k + 2) * 8 + c] + x.w * Wl[(k + 3) * 8 + c];
  }
  Yp[(size_t)row * 8 + c] = acc * dinv[row];
}

// ---------------- agg pass 1: 8 lanes per node ----------------
// U = dinv^2*(sum_src Yp + Yp[self]);  V = dinv*(sum_src dinv + dinv)   (lane 0)
__global__ __launch_bounds__(256) void k_agg1(const unsigned short* __restrict__ csr, const int2* __restrict__ offs2,
                                              const float* __restrict__ dinv, const float* __restrict__ Yp,
                                              float* __restrict__ U, float* __restrict__ V){
  int gid = blockIdx.x * 256 + threadIdx.x;
  int node = gid >> 3, c = gid & 7;
  if (node >= NN) return;
  int2 oe = offs2[node];
  int e = oe.x;
  const int e1 = oe.y;
  float a = 0.f, vd = 0.f;
  for (; e + 4 <= e1; e += 4){
    int s0 = csr[e], s1 = csr[e + 1], s2 = csr[e + 2], s3 = csr[e + 3];
    float y0 = Yp[(size_t)s0 * 8 + c], y1 = Yp[(size_t)s1 * 8 + c];
    float y2 = Yp[(size_t)s2 * 8 + c], y3 = Yp[(size_t)s3 * 8 + c];
    a += (y0 + y1) + (y2 + y3);
    if (c == 0) vd += (dinv[s0] + dinv[s1]) + (dinv[s2] + dinv[s3]);
  }
  for (; e < e1; ++e){
    int s0 = csr[e];
    a += Yp[(size_t)s0 * 8 + c];
    if (c == 0) vd += dinv[s0];
  }
  float di = dinv[node];
  U[(size_t)node * 8 + c] = di * di * (a + Yp[(size_t)node * 8 + c]);
  if (c == 0) V[node] = di * (vd + di);
}

// ---------------- agg pass 2: out = dinv*(sum_src U + U[self]) + V*c1 + c2 ----------------
__global__ __launch_bounds__(256) void k_agg2(const unsigned short* __restrict__ csr, const int2* __restrict__ offs2,
                                              const float* __restrict__ dinv, const float* __restrict__ U,
                                              const float* __restrict__ V, const float* __restrict__ c12,
                                              float* __restrict__ O){
  int gid = blockIdx.x * 256 + threadIdx.x;
  int node = gid >> 3, c = gid & 7;
  if (node >= NN) return;
  int2 oe = offs2[node];
  int e = oe.x;
  const int e1 = oe.y;
  float a = 0.f;
  for (; e + 4 <= e1; e += 4){
    int s0 = csr[e], s1 = csr[e + 1], s2 = csr[e + 2], s3 = csr[e + 3];
    float y0 = U[(size_t)s0 * 8 + c], y1 = U[(size_t)s1 * 8 + c];
    float y2 = U[(size_t)s2 * 8 + c], y3 = U[(size_t)s3 * 8 + c];
    a += (y0 + y1) + (y2 + y3);
  }
  for (; e < e1; ++e){
    int s0 = csr[e];
    a += U[(size_t)s0 * 8 + c];
  }
  float di = dinv[node];
  O[(size_t)node * 8 + c] = di * (a + U[(size_t)node * 8 + c]) + V[node] * c12[c] + c12[8 + c];
}

extern "C" void kernel_launch(void* const* d_in, const int* in_sizes, int n_in,
                              void* d_out, int out_size, void* d_ws, size_t ws_size,
                              hipStream_t stream) {
  const float* seq = (const float*)d_in[0];
  const int*   ei  = (const int*)d_in[1];
  const int*   esrc = ei;
  const int*   edst = ei + NE;
  const float* W1 = (const float*)d_in[2];
  const float* b1 = (const float*)d_in[3];
  const float* W2 = (const float*)d_in[4];
  const float* b2 = (const float*)d_in[5];
  const float* Wc = (const float*)d_in[6];
  const float* bc = (const float*)d_in[7];
  float* out = (float*)d_out;

  char* ws = (char*)d_ws;
  size_t o = 0;
  auto alloc = [&](size_t bytes) -> void* {
    void* p = ws + o;
    o += (bytes + 255) & ~(size_t)255;
    return p;
  };
  int*      bh    = (int*)alloc((size_t)NSB * NBK * 4);
  int*      boff  = (int*)alloc((size_t)NSB * NBK * 4);
  int*      btot  = (int*)alloc((size_t)NBK * 4);
  uint32_t* ebuf  = (uint32_t*)alloc((size_t)NBK * CAP * 4);
  unsigned short* csr = (unsigned short*)alloc((size_t)NBK * CAP * 2);
  int2*     offs2 = (int2*)alloc((size_t)NN * 8);
  float*    dinv  = (float*)alloc((size_t)NN * 4);
  float*    Wcb   = (float*)alloc(2048 * 4);
  float*    c12   = (float*)alloc(16 * 4);
  float*    Yp    = (float*)alloc((size_t)NN * 8 * 4);
  float*    U     = (float*)alloc((size_t)NN * 8 * 4);
  float*    V     = (float*)alloc((size_t)NN * 4);

  k_wcombo <<<9, 256, 0, stream>>>(W1, b1, W2, b2, Wc, bc, Wcb, c12);
  k_hist   <<<NSB, 256, 0, stream>>>(edst, bh);
  k_bscan  <<<NBK, NSB, 0, stream>>>(bh, boff, btot);
  k_scat   <<<NSB, 256, 0, stream>>>(esrc, edst, boff, ebuf);
  k_csr    <<<NBK, 256, 0, stream>>>(ebuf, btot, dinv, offs2, csr);
  k_y      <<<(NN * 8 + 255) / 256, 256, 0, stream>>>(seq, Wcb, dinv, Yp);
  k_agg1   <<<(NN * 8 + 255) / 256, 256, 0, stream>>>(csr, offs2, dinv, Yp, U, V);
  k_agg2   <<<(NN * 8 + 255) / 256, 256, 0, stream>>>(csr, offs2, dinv, U, V, c12, out);
}

// Round 10
// 88.897 us; speedup vs baseline: 3.0269x; 1.1165x over previous
//
#include <hip/hip_runtime.h>
#include <hip/hip_bf16.h>
#include <stdint.h>

#define NN 50000
#define NE 1600000
#define BSH 7            // bucket = 128 dst nodes
#define NBK 391          // ceil(NN/128)
#define CAP 4608         // slots per bucket (mean 4092, sigma~64, +8 sigma)
#define NSB 256          // edge-pass blocks
#define ECH 6250         // edges per block (NSB*ECH == NE exactly)
#define NYB 1563         // y blocks = ceil(NN*8/256)

// ---------------- launch 1: [wcombo: blocks 0-8 | hist: blocks 9..264] ----------------
__global__ __launch_bounds__(256) void k_iw(const float* __restrict__ W1, const float* __restrict__ b1,
                                            const float* __restrict__ W2, const float* __restrict__ b2,
                                            const float* __restrict__ Wc, const float* __restrict__ bc,
                                            float* __restrict__ Wcombo, float* __restrict__ c12,
                                            const int* __restrict__ dst, int* __restrict__ bh){
  __shared__ float M1[128 * 8];
  __shared__ int h[4 * NBK];
  const int t = threadIdx.x;
  if (blockIdx.x < 9){
    // M1 = W2@Wc (recomputed per block)
    for (int idx = t; idx < 1024; idx += 256){
      int k = idx >> 3, c = idx & 7;
      float s = 0.f;
      for (int j = 0; j < 64; ++j) s += W2[k * 64 + j] * Wc[j * 8 + c];
      M1[idx] = s;
    }
    __syncthreads();
    if (blockIdx.x < 8){
      int i = blockIdx.x * 32 + (t >> 3), c = t & 7;
      float s = 0.f;
      for (int k = 0; k < 128; ++k) s += W1[i * 128 + k] * M1[k * 8 + c];
      Wcombo[i * 8 + c] = s;
    } else {
      if (t < 8){
        float s = 0.f;
        for (int k = 0; k < 128; ++k) s += b1[k] * M1[k * 8 + t];
        c12[t] = s;
      } else if (t < 16){
        int c = t - 8;
        float s = bc[c];
        for (int k = 0; k < 64; ++k) s += b2[k] * Wc[k * 8 + c];
        c12[t] = s;
      }
    }
  } else {
    const int hb = blockIdx.x - 9;
    for (int i = t; i < 4 * NBK; i += 256) h[i] = 0;
    __syncthreads();
    const int wv = (t >> 6) * NBK;
    const int e0 = hb * ECH;
    for (int e = e0 + t; e < e0 + ECH; e += 256)
      atomicAdd(&h[wv + (dst[e] >> BSH)], 1);
    __syncthreads();
    for (int i = t; i < NBK; i += 256)
      bh[(size_t)hb * NBK + i] = h[i] + h[NBK + i] + h[2 * NBK + i] + h[3 * NBK + i];
  }
}

// ---------------- launch 2: per-bucket exclusive scan over the NSB blocks ----------------
__global__ __launch_bounds__(NSB) void k_bscan(const int* __restrict__ bh, int* __restrict__ boff,
                                               int* __restrict__ btot){
  __shared__ int lds[NSB];
  const int b = blockIdx.x;
  int v = bh[(size_t)threadIdx.x * NBK + b];
  lds[threadIdx.x] = v;
  __syncthreads();
  for (int ofs = 1; ofs < NSB; ofs <<= 1){
    int t = (threadIdx.x >= ofs) ? lds[threadIdx.x - ofs] : 0;
    __syncthreads();
    lds[threadIdx.x] += t;
    __syncthreads();
  }
  boff[(size_t)threadIdx.x * NBK + b] = lds[threadIdx.x] - v;
  if (threadIdx.x == NSB - 1) btot[b] = lds[NSB - 1];
}

// ---------------- launch 3: [scat: blocks 0..255 | Yraw = X@Wcombo: blocks 256+] ----------------
__global__ __launch_bounds__(256) void k_sy(const int* __restrict__ src, const int* __restrict__ dst,
                                            const int* __restrict__ boff, uint32_t* __restrict__ ebuf,
                                            const float* __restrict__ X, const float* __restrict__ Wcombo,
                                            float* __restrict__ Yraw){
  __shared__ int ctr[NBK];
  __shared__ float Wl[2048];
  const int t = threadIdx.x;
  if (blockIdx.x < NSB){
    for (int i = t; i < NBK; i += 256)
      ctr[i] = i * CAP + boff[(size_t)blockIdx.x * NBK + i];
    __syncthreads();
    const int e0 = blockIdx.x * ECH;
    for (int e = e0 + t; e < e0 + ECH; e += 256){
      int d = dst[e];
      int s = src[e];
      int p = atomicAdd(&ctr[d >> BSH], 1);
      ebuf[p] = ((uint32_t)s << 16) | (uint32_t)d;
    }
  } else {
    for (int i = t; i < 2048; i += 256) Wl[i] = Wcombo[i];
    __syncthreads();
    int gid = (blockIdx.x - NSB) * 256 + t;
    int row = gid >> 3, c = gid & 7;
    if (row >= NN) return;
    const float* Xr = X + (size_t)row * 256;
    float acc = 0.f;
    #pragma unroll 8
    for (int k = 0; k < 256; k += 4){
      float4 x = *(const float4*)(Xr + k);
      acc += x.x * Wl[k * 8 + c] + x.y * Wl[(k + 1) * 8 + c]
           + x.z * Wl[(k + 2) * 8 + c] + x.w * Wl[(k + 3) * 8 + c];
    }
    Yraw[(size_t)row * 8 + c] = acc;
  }
}

// ---------------- launch 4: per-bucket LDS-staged degree + scan + dinv + offs2 + csr ----------------
__global__ __launch_bounds__(256) void k_csr(const uint32_t* __restrict__ ebuf, const int* __restrict__ btot,
                                             float* __restrict__ dinv, int2* __restrict__ offs2,
                                             unsigned short* __restrict__ csr){
  __shared__ uint32_t lede[CAP];
  __shared__ unsigned short lcsr[CAP];
  __shared__ int h[128];
  __shared__ int sb[128];
  const int t = threadIdx.x;
  const int b = blockIdx.x;
  const int base = b * CAP;
  const int cnt = btot[b];
  for (int i = t; i < cnt; i += 256) lede[i] = ebuf[base + i];
  if (t < 128) h[t] = 0;
  __syncthreads();
  for (int i = t; i < cnt; i += 256)
    atomicAdd(&h[lede[i] & 127], 1);
  __syncthreads();
  int deg = (t < 128) ? h[t] : 0;
  for (int ofs = 1; ofs < 128; ofs <<= 1){
    int tv = (t >= ofs && t < 128) ? h[t - ofs] : 0;
    __syncthreads();
    if (t < 128) h[t] += tv;
    __syncthreads();
  }
  int excl = (t < 128) ? (h[t] - deg) : 0;
  int node = (b << BSH) + t;
  if (t < 128 && node < NN){
    dinv[node] = rsqrtf((float)(deg + 1));
    offs2[node] = make_int2(base + excl, base + excl + deg);
  }
  __syncthreads();
  if (t < 128) sb[t] = excl;
  __syncthreads();
  for (int i = t; i < cnt; i += 256){
    uint32_t v = lede[i];
    int p = atomicAdd(&sb[v & 127], 1);
    lcsr[p] = (unsigned short)(v >> 16);
  }
  __syncthreads();
  uint32_t* dstw = (uint32_t*)(csr + base);
  const uint32_t* srcw = (const uint32_t*)lcsr;
  int nw = (cnt + 1) >> 1;
  for (int i = t; i < nw; i += 256) dstw[i] = srcw[i];
}

// ---------------- launch 5: agg pass 1, 8 lanes/node ----------------
// U = di^2*(sum_s dinv_s*Yraw_s + di*Yraw_d);  V = di*(sum_s dinv_s + di)
__global__ __launch_bounds__(256) void k_agg1(const unsigned short* __restrict__ csr, const int2* __restrict__ offs2,
                                              const float* __restrict__ dinv, const float* __restrict__ Y,
                                              float* __restrict__ U, float* __restrict__ V){
  int gid = blockIdx.x * 256 + threadIdx.x;
  int node = gid >> 3, c = gid & 7;
  if (node >= NN) return;
  int2 oe = offs2[node];
  int e = oe.x;
  const int e1 = oe.y;
  float a = 0.f, vd = 0.f;
  for (; e + 4 <= e1; e += 4){
    int s0 = csr[e], s1 = csr[e + 1], s2 = csr[e + 2], s3 = csr[e + 3];
    float d0 = dinv[s0], d1 = dinv[s1], d2 = dinv[s2], d3 = dinv[s3];
    float y0 = Y[(size_t)s0 * 8 + c], y1 = Y[(size_t)s1 * 8 + c];
    float y2 = Y[(size_t)s2 * 8 + c], y3 = Y[(size_t)s3 * 8 + c];
    a += (d0 * y0 + d1 * y1) + (d2 * y2 + d3 * y3);
    vd += (d0 + d1) + (d2 + d3);
  }
  for (; e < e1; ++e){
    int s0 = csr[e];
    float d0 = dinv[s0];
    a += d0 * Y[(size_t)s0 * 8 + c];
    vd += d0;
  }
  float di = dinv[node];
  U[(size_t)node * 8 + c] = di * di * (a + di * Y[(size_t)node * 8 + c]);
  if (c == 0) V[node] = di * (vd + di);
}

// ---------------- launch 6: agg pass 2: out = di*(sum_s U_s + U_d) + V*c1 + c2 ----------------
__global__ __launch_bounds__(256) void k_agg2(const unsigned short* __restrict__ csr, const int2* __restrict__ offs2,
                                              const float* __restrict__ dinv, const float* __restrict__ U,
                                              const float* __restrict__ V, const float* __restrict__ c12,
                                              float* __restrict__ O){
  int gid = blockIdx.x * 256 + threadIdx.x;
  int node = gid >> 3, c = gid & 7;
  if (node >= NN) return;
  int2 oe = offs2[node];
  int e = oe.x;
  const int e1 = oe.y;
  float a = 0.f;
  for (; e + 4 <= e1; e += 4){
    int s0 = csr[e], s1 = csr[e + 1], s2 = csr[e + 2], s3 = csr[e + 3];
    float y0 = U[(size_t)s0 * 8 + c], y1 = U[(size_t)s1 * 8 + c];
    float y2 = U[(size_t)s2 * 8 + c], y3 = U[(size_t)s3 * 8 + c];
    a += (y0 + y1) + (y2 + y3);
  }
  for (; e < e1; ++e){
    int s0 = csr[e];
    a += U[(size_t)s0 * 8 + c];
  }
  float di = dinv[node];
  O[(size_t)node * 8 + c] = di * (a + U[(size_t)node * 8 + c]) + V[node] * c12[c] + c12[8 + c];
}

extern "C" void kernel_launch(void* const* d_in, const int* in_sizes, int n_in,
                              void* d_out, int out_size, void* d_ws, size_t ws_size,
                              hipStream_t stream) {
  const float* seq = (const float*)d_in[0];
  const int*   ei  = (const int*)d_in[1];
  const int*   esrc = ei;
  const int*   edst = ei + NE;
  const float* W1 = (const float*)d_in[2];
  const float* b1 = (const float*)d_in[3];
  const float* W2 = (const float*)d_in[4];
  const float* b2 = (const float*)d_in[5];
  const float* Wc = (const float*)d_in[6];
  const float* bc = (const float*)d_in[7];
  float* out = (float*)d_out;

  char* ws = (char*)d_ws;
  size_t o = 0;
  auto alloc = [&](size_t bytes) -> void* {
    void* p = ws + o;
    o += (bytes + 255) & ~(size_t)255;
    return p;
  };
  int*      bh    = (int*)alloc((size_t)NSB * NBK * 4);
  int*      boff  = (int*)alloc((size_t)NSB * NBK * 4);
  int*      btot  = (int*)alloc((size_t)NBK * 4);
  uint32_t* ebuf  = (uint32_t*)alloc((size_t)NBK * CAP * 4);
  unsigned short* csr = (unsigned short*)alloc((size_t)NBK * CAP * 2);
  int2*     offs2 = (int2*)alloc((size_t)NN * 8);
  float*    dinv  = (float*)alloc((size_t)NN * 4);
  float*    Wcb   = (float*)alloc(2048 * 4);
  float*    c12   = (float*)alloc(16 * 4);
  float*    Yraw  = (float*)alloc((size_t)NN * 8 * 4);
  float*    U     = (float*)alloc((size_t)NN * 8 * 4);
  float*    V     = (float*)alloc((size_t)NN * 4);

  k_iw     <<<9 + NSB, 256, 0, stream>>>(W1, b1, W2, b2, Wc, bc, Wcb, c12, edst, bh);
  k_bscan  <<<NBK, NSB, 0, stream>>>(bh, boff, btot);
  k_sy     <<<NSB + NYB, 256, 0, stream>>>(esrc, edst, boff, ebuf, seq, Wcb, Yraw);
  k_csr    <<<NBK, 256, 0, stream>>>(ebuf, btot, dinv, offs2, csr);
  k_agg1   <<<NYB, 256, 0, stream>>>(csr, offs2, dinv, Yraw, U, V);
  k_agg2   <<<NYB, 256, 0, stream>>>(csr, offs2, dinv, U, V, c12, out);
}